// Round 2
// baseline (910.302 us; speedup 1.0000x reference)
//
#include <hip/hip_runtime.h>

#define DM 768
#define SL 2048
#define NB 2
#define NH 12
#define DK 64

typedef __bf16 bf16x8 __attribute__((ext_vector_type(8)));
typedef float f32x4 __attribute__((ext_vector_type(4)));

__device__ __forceinline__ float bf2f(unsigned short u) {
  return __uint_as_float(((unsigned int)u) << 16);
}
__device__ __forceinline__ unsigned short f2bf(float f) {
  unsigned int u = __float_as_uint(f);
  u += 0x7fff + ((u >> 16) & 1);  // RNE
  return (unsigned short)(u >> 16);
}

// C[m][n] = scale * sum_k A[m][k]*B[n][k] + bias[n]
// A modes (AM) / B modes (BM): 0 = bf16 in global, 1 = f32 -> bf16 staging,
// 2 = f32 -> split hi/lo bf16 staging (3-MFMA compensated product; AM==2 requires BM==2).
// OF32: output f32 (else bf16). bias always f32 (or nullptr).
// grid: (N/64, M/64, nz); z -> zb=z/zdiv, zh=z%zdiv
template <int AM, int BM, bool OF32>
__global__ __launch_bounds__(256) void gemm_bt_t(
    const void* __restrict__ Av, int lda, long sAb, long sAh,
    const void* __restrict__ Bv, int ldb, long sBb, long sBh,
    void* __restrict__ Cv, int ldc, long sCb, long sCh,
    const float* __restrict__ bias, float scale, int K, int zdiv) {
  constexpr bool SPLIT = (AM == 2);
  const int z = blockIdx.z, zb = z / zdiv, zh = z % zdiv;
  const long aoff = (long)zb * sAb + (long)zh * sAh;
  const long boff = (long)zb * sBb + (long)zh * sBh;
  const long coff = (long)zb * sCb + (long)zh * sCh;
  const int tm = blockIdx.y * 64, tn = blockIdx.x * 64;
  __shared__ __align__(16) unsigned short As[64][40];  // 80B rows: 16B-aligned, 2-way bank alias (free, m136)
  __shared__ __align__(16) unsigned short Bs[64][40];
  __shared__ __align__(16) unsigned short Al[SPLIT ? 64 : 1][40];
  __shared__ __align__(16) unsigned short Bl[SPLIT ? 64 : 1][40];
  const int tid = threadIdx.x;
  const int lrow = tid >> 2, lcol = (tid & 3) * 8;
  const int lane = tid & 63, wave = tid >> 6;
  const int wm = (wave >> 1) * 32, wn = (wave & 1) * 32;
  const int fr = lane & 15, quad = lane >> 4;
  f32x4 acc[2][2] = {};
  for (int k0 = 0; k0 < K; k0 += 32) {
    // ---- stage A tile ----
    if constexpr (AM == 0) {
      const unsigned short* Ab = (const unsigned short*)Av + aoff;
      *(uint4*)&As[lrow][lcol] = *(const uint4*)(Ab + (long)(tm + lrow) * lda + k0 + lcol);
    } else {
      const float* Af = (const float*)Av + aoff + (long)(tm + lrow) * lda + k0 + lcol;
      float4 f0 = *(const float4*)Af;
      float4 f1 = *(const float4*)(Af + 4);
      float ff[8] = {f0.x, f0.y, f0.z, f0.w, f1.x, f1.y, f1.z, f1.w};
      unsigned short hi[8];
#pragma unroll
      for (int i = 0; i < 8; ++i) hi[i] = f2bf(ff[i]);
      *(uint4*)&As[lrow][lcol] = *(const uint4*)hi;
      if constexpr (SPLIT) {
        unsigned short lo[8];
#pragma unroll
        for (int i = 0; i < 8; ++i) lo[i] = f2bf(ff[i] - bf2f(hi[i]));
        *(uint4*)&Al[lrow][lcol] = *(const uint4*)lo;
      }
    }
    // ---- stage B tile ----
    if constexpr (BM == 0) {
      const unsigned short* Bb = (const unsigned short*)Bv + boff;
      *(uint4*)&Bs[lrow][lcol] = *(const uint4*)(Bb + (long)(tn + lrow) * ldb + k0 + lcol);
    } else {
      const float* Bf = (const float*)Bv + boff + (long)(tn + lrow) * ldb + k0 + lcol;
      float4 f0 = *(const float4*)Bf;
      float4 f1 = *(const float4*)(Bf + 4);
      float ff[8] = {f0.x, f0.y, f0.z, f0.w, f1.x, f1.y, f1.z, f1.w};
      unsigned short hi[8];
#pragma unroll
      for (int i = 0; i < 8; ++i) hi[i] = f2bf(ff[i]);
      *(uint4*)&Bs[lrow][lcol] = *(const uint4*)hi;
      if constexpr (SPLIT) {
        unsigned short lo[8];
#pragma unroll
        for (int i = 0; i < 8; ++i) lo[i] = f2bf(ff[i] - bf2f(hi[i]));
        *(uint4*)&Bl[lrow][lcol] = *(const uint4*)lo;
      }
    }
    __syncthreads();
    bf16x8 a0 = *(const bf16x8*)&As[wm + fr][quad * 8];
    bf16x8 a1 = *(const bf16x8*)&As[wm + 16 + fr][quad * 8];
    bf16x8 b0 = *(const bf16x8*)&Bs[wn + fr][quad * 8];
    bf16x8 b1 = *(const bf16x8*)&Bs[wn + 16 + fr][quad * 8];
    acc[0][0] = __builtin_amdgcn_mfma_f32_16x16x32_bf16(a0, b0, acc[0][0], 0, 0, 0);
    acc[0][1] = __builtin_amdgcn_mfma_f32_16x16x32_bf16(a0, b1, acc[0][1], 0, 0, 0);
    acc[1][0] = __builtin_amdgcn_mfma_f32_16x16x32_bf16(a1, b0, acc[1][0], 0, 0, 0);
    acc[1][1] = __builtin_amdgcn_mfma_f32_16x16x32_bf16(a1, b1, acc[1][1], 0, 0, 0);
    if constexpr (SPLIT) {
      bf16x8 c0 = *(const bf16x8*)&Al[wm + fr][quad * 8];
      bf16x8 c1 = *(const bf16x8*)&Al[wm + 16 + fr][quad * 8];
      bf16x8 d0 = *(const bf16x8*)&Bl[wn + fr][quad * 8];
      bf16x8 d1 = *(const bf16x8*)&Bl[wn + 16 + fr][quad * 8];
      acc[0][0] = __builtin_amdgcn_mfma_f32_16x16x32_bf16(c0, b0, acc[0][0], 0, 0, 0);
      acc[0][1] = __builtin_amdgcn_mfma_f32_16x16x32_bf16(c0, b1, acc[0][1], 0, 0, 0);
      acc[1][0] = __builtin_amdgcn_mfma_f32_16x16x32_bf16(c1, b0, acc[1][0], 0, 0, 0);
      acc[1][1] = __builtin_amdgcn_mfma_f32_16x16x32_bf16(c1, b1, acc[1][1], 0, 0, 0);
      acc[0][0] = __builtin_amdgcn_mfma_f32_16x16x32_bf16(a0, d0, acc[0][0], 0, 0, 0);
      acc[0][1] = __builtin_amdgcn_mfma_f32_16x16x32_bf16(a0, d1, acc[0][1], 0, 0, 0);
      acc[1][0] = __builtin_amdgcn_mfma_f32_16x16x32_bf16(a1, d0, acc[1][0], 0, 0, 0);
      acc[1][1] = __builtin_amdgcn_mfma_f32_16x16x32_bf16(a1, d1, acc[1][1], 0, 0, 0);
    }
    __syncthreads();
  }
#pragma unroll
  for (int sm = 0; sm < 2; ++sm)
#pragma unroll
    for (int sn = 0; sn < 2; ++sn) {
      const int gcol = tn + wn + sn * 16 + fr;
      const float bv = bias ? bias[gcol] : 0.0f;
#pragma unroll
      for (int r = 0; r < 4; ++r) {
        const int grow = tm + wm + sm * 16 + quad * 4 + r;
        const float val = acc[sm][sn][r] * scale + bv;
        if constexpr (OF32)
          ((float*)Cv)[coff + (long)grow * ldc + gcol] = val;
        else
          ((unsigned short*)Cv)[coff + (long)grow * ldc + gcol] = f2bf(val);
      }
    }
}

// Row softmax, in place, f32. One wave per row of SL=2048. grid: rows/4, block 256.
__global__ __launch_bounds__(256) void softmax_rows(float* __restrict__ attn) {
  const int wave = threadIdx.x >> 6, lane = threadIdx.x & 63;
  const long row = (long)blockIdx.x * 4 + wave;
  float* p = attn + row * SL;
  float v[32];
  float m = -1e30f;
#pragma unroll
  for (int j = 0; j < 8; ++j) {
    float4 d = *(const float4*)(p + j * 256 + lane * 4);
    v[j * 4 + 0] = d.x; v[j * 4 + 1] = d.y; v[j * 4 + 2] = d.z; v[j * 4 + 3] = d.w;
    m = fmaxf(m, fmaxf(fmaxf(d.x, d.y), fmaxf(d.z, d.w)));
  }
#pragma unroll
  for (int off = 32; off; off >>= 1) m = fmaxf(m, __shfl_xor(m, off, 64));
  float sum = 0.0f;
#pragma unroll
  for (int i = 0; i < 32; ++i) {
    float e = __expf(v[i] - m);
    v[i] = e;
    sum += e;
  }
#pragma unroll
  for (int off = 32; off; off >>= 1) sum += __shfl_xor(sum, off, 64);
  const float inv = 1.0f / sum;
#pragma unroll
  for (int j = 0; j < 8; ++j) {
    float4 d;
    d.x = v[j * 4 + 0] * inv; d.y = v[j * 4 + 1] * inv;
    d.z = v[j * 4 + 2] * inv; d.w = v[j * 4 + 3] * inv;
    *(float4*)(p + j * 256 + lane * 4) = d;
  }
}

// x[m][n] = sum_k P[m][k]*V[k][n]; P:[2048,2048] f32 per z, V:[2048,64] bf16 row-stride DM.
// out bf16. grid: (1, SL/64, NB*NH)
__global__ __launch_bounds__(256) void gemm_nn64(
    const float* __restrict__ P, long sPz,
    const unsigned short* __restrict__ V, long sVb, long sVh,
    unsigned short* __restrict__ C, long sCb, long sCh, int zdiv) {
  const int z = blockIdx.z, zb = z / zdiv, zh = z % zdiv;
  P += (long)z * sPz;
  V += (long)zb * sVb + (long)zh * sVh;
  C += (long)zb * sCb + (long)zh * sCh;
  const int tm = blockIdx.y * 64;
  __shared__ __align__(16) unsigned short Ps[64][40];
  __shared__ __align__(16) unsigned short Vt[64][40];  // transposed: Vt[n][k]
  const int tid = threadIdx.x;
  const int arow = tid >> 2, acol = (tid & 3) * 8;
  const int vkr = tid >> 3, vnc = (tid & 7) * 8;
  const int lane = tid & 63, wave = tid >> 6;
  const int wm = (wave >> 1) * 32, wn = (wave & 1) * 32;
  const int fr = lane & 15, quad = lane >> 4;
  f32x4 acc[2][2] = {};
  for (int k0 = 0; k0 < SL; k0 += 32) {
    const float* Pf = P + (long)(tm + arow) * SL + k0 + acol;
    float4 f0 = *(const float4*)Pf;
    float4 f1 = *(const float4*)(Pf + 4);
    float ff[8] = {f0.x, f0.y, f0.z, f0.w, f1.x, f1.y, f1.z, f1.w};
    unsigned short hi[8];
#pragma unroll
    for (int i = 0; i < 8; ++i) hi[i] = f2bf(ff[i]);
    *(uint4*)&Ps[arow][acol] = *(const uint4*)hi;
    uint4 vv = *(const uint4*)(V + (long)(k0 + vkr) * DM + vnc);
    const unsigned short* vs = (const unsigned short*)&vv;
#pragma unroll
    for (int i = 0; i < 8; ++i) Vt[vnc + i][vkr] = vs[i];
    __syncthreads();
    bf16x8 a0 = *(const bf16x8*)&Ps[wm + fr][quad * 8];
    bf16x8 a1 = *(const bf16x8*)&Ps[wm + 16 + fr][quad * 8];
    bf16x8 b0 = *(const bf16x8*)&Vt[wn + fr][quad * 8];
    bf16x8 b1 = *(const bf16x8*)&Vt[wn + 16 + fr][quad * 8];
    acc[0][0] = __builtin_amdgcn_mfma_f32_16x16x32_bf16(a0, b0, acc[0][0], 0, 0, 0);
    acc[0][1] = __builtin_amdgcn_mfma_f32_16x16x32_bf16(a0, b1, acc[0][1], 0, 0, 0);
    acc[1][0] = __builtin_amdgcn_mfma_f32_16x16x32_bf16(a1, b0, acc[1][0], 0, 0, 0);
    acc[1][1] = __builtin_amdgcn_mfma_f32_16x16x32_bf16(a1, b1, acc[1][1], 0, 0, 0);
    __syncthreads();
  }
#pragma unroll
  for (int sm = 0; sm < 2; ++sm)
#pragma unroll
    for (int sn = 0; sn < 2; ++sn) {
      const int gcol = wn + sn * 16 + fr;
#pragma unroll
      for (int r = 0; r < 4; ++r) {
        const int grow = tm + wm + sm * 16 + quad * 4 + r;
        C[(long)grow * DM + gcol] = f2bf(acc[sm][sn][r]);
      }
    }
}

extern "C" void kernel_launch(void* const* d_in, const int* in_sizes, int n_in,
                              void* d_out, int out_size, void* d_ws, size_t ws_size,
                              hipStream_t stream) {
  const float* q  = (const float*)d_in[0];
  const float* k  = (const float*)d_in[1];
  const float* v  = (const float*)d_in[2];
  const float* wq = (const float*)d_in[3];
  const float* bq = (const float*)d_in[4];
  const float* wk = (const float*)d_in[5];
  const float* bk = (const float*)d_in[6];
  const float* wv = (const float*)d_in[7];
  const float* bv = (const float*)d_in[8];
  const float* wo = (const float*)d_in[9];
  const float* bo = (const float*)d_in[10];

  float* out  = (float*)d_out;
  float* attn = out + (long)NB * SL * DM;  // f32 attn region (also raw-score scratch)

  const long NE = (long)NB * SL * DM;  // 3,145,728 elements
  float* Qf = (float*)d_ws;            // f32 Q (split-bf16 source for scores)
  float* Kf = Qf + NE;                 // f32 K
  unsigned short* Vb = (unsigned short*)(Kf + NE);  // bf16 V
  unsigned short* Xb = Vb + NE;                     // bf16 attn@V    (~37.7 MB total)

  const dim3 blk(256);
  const dim3 gp(DM / 64, (NB * SL) / 64, 1);

  // Q/K projections: split-bf16 (3-MFMA) for precision, f32 out
  gemm_bt_t<2, 2, true><<<gp, blk, 0, stream>>>(q, DM, 0L, 0L, wq, DM, 0L, 0L,
                                                Qf, DM, 0L, 0L, bq, 1.0f, DM, 1);
  gemm_bt_t<2, 2, true><<<gp, blk, 0, stream>>>(k, DM, 0L, 0L, wk, DM, 0L, 0L,
                                                Kf, DM, 0L, 0L, bk, 1.0f, DM, 1);
  // V projection: plain bf16 path, bf16 out
  gemm_bt_t<1, 1, false><<<gp, blk, 0, stream>>>(v, DM, 0L, 0L, wv, DM, 0L, 0L,
                                                 Vb, DM, 0L, 0L, bv, 1.0f, DM, 1);

  // scores = Q @ K^T / 8 per (b,h): split-bf16, raw f32 into attn region
  const dim3 gs(SL / 64, SL / 64, NB * NH);
  gemm_bt_t<2, 2, true><<<gs, blk, 0, stream>>>(Qf, DM, (long)SL * DM, 64L,
                                                Kf, DM, (long)SL * DM, 64L,
                                                attn, SL, (long)NH * SL * SL, (long)SL * SL,
                                                nullptr, 0.125f, DK, NH);

  // softmax rows in place (f32)
  softmax_rows<<<dim3(NB * NH * SL / 4), blk, 0, stream>>>(attn);

  // x = attn @ V  (bf16 out)
  const dim3 ga(1, SL / 64, NB * NH);
  gemm_nn64<<<ga, blk, 0, stream>>>(attn, (long)SL * SL,
                                    Vb, (long)SL * DM, 64L,
                                    Xb, (long)SL * DM, 64L, NH);

  // out = x @ w_o^T + b_o  (f32 out)
  gemm_bt_t<0, 1, true><<<gp, blk, 0, stream>>>(Xb, DM, 0L, 0L, wo, DM, 0L, 0L,
                                                out, DM, 0L, 0L, bo, 1.0f, DM, 1);
}